// Round 2
// baseline (327.874 us; speedup 1.0000x reference)
//
#include <hip/hip_runtime.h>
#include <stdint.h>
#include <math.h>

typedef __attribute__((ext_vector_type(8))) short short8;
typedef __attribute__((ext_vector_type(4))) float f32x4;

__device__ __forceinline__ ushort f2bf(float f) {
    union { float f; uint32_t i; } v; v.f = f;
    uint32_t r = v.i + 0x7FFFu + ((v.i >> 16) & 1u);
    return (ushort)(r >> 16);
}
__device__ __forceinline__ float bf2f(ushort u) {
    union { uint32_t i; float f; } v; v.i = ((uint32_t)u) << 16; return v.f;
}

// ---------------------------------------------------------------------------
// Kernel 1: input transpose [B,T,C,L] (f32) -> x[token][c] (f32) + LN1 -> xln (bf16)
// one block per token (4096 blocks x 512 threads)
__global__ __launch_bounds__(512) void prep_kernel(const float* __restrict__ in,
        const float* __restrict__ g, const float* __restrict__ bta,
        float* __restrict__ x, ushort* __restrict__ xln) {
    int token = blockIdx.x;          // 0..4095
    int c = threadIdx.x;             // 0..511
    int b = token >> 11;
    int n = token & 2047;
    int t = n >> 8;
    int l = n & 255;
    size_t iidx = (((size_t)((b * 8 + t) * 512 + c)) << 8) + l;
    float v = in[iidx];
    x[(size_t)token * 512 + c] = v;

    float s = v, s2 = v * v;
    #pragma unroll
    for (int off = 32; off > 0; off >>= 1) {
        s  += __shfl_down(s, off, 64);
        s2 += __shfl_down(s2, off, 64);
    }
    __shared__ float ps[8], ps2[8];
    int wave = threadIdx.x >> 6, lane = threadIdx.x & 63;
    if (lane == 0) { ps[wave] = s; ps2[wave] = s2; }
    __syncthreads();
    float mu = 0.f, m2 = 0.f;
    #pragma unroll
    for (int i = 0; i < 8; i++) { mu += ps[i]; m2 += ps2[i]; }
    mu *= (1.0f / 512.0f); m2 *= (1.0f / 512.0f);
    float rs = rsqrtf(m2 - mu * mu + 1e-5f);
    float y = (v - mu) * rs * g[c] + bta[c];
    xln[(size_t)token * 512 + c] = f2bf(y);
}

// ---------------------------------------------------------------------------
// LN2 over f32 input -> bf16
__global__ __launch_bounds__(512) void ln2_kernel(const float* __restrict__ xin,
        const float* __restrict__ g, const float* __restrict__ bta,
        ushort* __restrict__ out) {
    int token = blockIdx.x;
    int c = threadIdx.x;
    float v = xin[(size_t)token * 512 + c];
    float s = v, s2 = v * v;
    #pragma unroll
    for (int off = 32; off > 0; off >>= 1) {
        s  += __shfl_down(s, off, 64);
        s2 += __shfl_down(s2, off, 64);
    }
    __shared__ float ps[8], ps2[8];
    int wave = threadIdx.x >> 6, lane = threadIdx.x & 63;
    if (lane == 0) { ps[wave] = s; ps2[wave] = s2; }
    __syncthreads();
    float mu = 0.f, m2 = 0.f;
    #pragma unroll
    for (int i = 0; i < 8; i++) { mu += ps[i]; m2 += ps2[i]; }
    mu *= (1.0f / 512.0f); m2 *= (1.0f / 512.0f);
    float rs = rsqrtf(m2 - mu * mu + 1e-5f);
    float y = (v - mu) * rs * g[c] + bta[c];
    out[(size_t)token * 512 + c] = f2bf(y);
}

// ---------------------------------------------------------------------------
// Generic MFMA GEMM: C = A[MxK](bf16) @ B[KxN](f32 weights) + bias(f32).
// 64x64 block tile, BK=32, 256 threads (4 waves, each 16 rows x 64 cols).
#define EPI_BF16   0
#define EPI_F32RES 1
#define EPI_GELU   2

template<int EPI>
__global__ __launch_bounds__(256) void gemm_kernel(
        const ushort* __restrict__ A, const float* __restrict__ Bw,
        const float* __restrict__ bias, const float* __restrict__ resid,
        float* __restrict__ outF, ushort* __restrict__ outB,
        int M, int N, int K) {
    __shared__ __align__(16) ushort As[64][40];   // [m][k], stride 40 shorts = 80B
    __shared__ __align__(16) ushort Bs[64][40];   // transposed: [n][k]
    int tid = threadIdx.x;
    int wave = tid >> 6, lane = tid & 63;
    int l16 = lane & 15, quad = lane >> 4;
    int m0 = blockIdx.y * 64, n0 = blockIdx.x * 64;
    int am = tid >> 2, ak = (tid & 3) * 8;        // A staging: 16B per thread
    int bn = tid & 63, bk = (tid >> 6) * 8;       // B staging: 8-element k strip
    f32x4 acc[4] = {};
    for (int k0 = 0; k0 < K; k0 += 32) {
        *(short8*)&As[am][ak] = *(const short8*)(A + (size_t)(m0 + am) * K + k0 + ak);
        short8 bv;
        #pragma unroll
        for (int i = 0; i < 8; i++)
            bv[i] = (short)f2bf(Bw[(size_t)(k0 + bk + i) * N + n0 + bn]);
        *(short8*)&Bs[bn][bk] = bv;
        __syncthreads();
        short8 af = *(short8*)&As[wave * 16 + l16][quad * 8];
        #pragma unroll
        for (int s = 0; s < 4; s++) {
            short8 bf = *(short8*)&Bs[s * 16 + l16][quad * 8];
            acc[s] = __builtin_amdgcn_mfma_f32_16x16x32_bf16(af, bf, acc[s], 0, 0, 0);
        }
        __syncthreads();
    }
    int row_base = m0 + wave * 16 + quad * 4;
    #pragma unroll
    for (int s = 0; s < 4; s++) {
        int col = n0 + s * 16 + l16;
        float bvf = bias[col];
        #pragma unroll
        for (int r = 0; r < 4; r++) {
            int row = row_base + r;
            float v = acc[s][r] + bvf;
            if constexpr (EPI == EPI_F32RES) {
                outF[(size_t)row * N + col] = v + resid[(size_t)row * N + col];
            } else if constexpr (EPI == EPI_GELU) {
                float gg = 0.5f * v * (1.0f + erff(v * 0.70710678118654752f));
                outB[(size_t)row * N + col] = f2bf(gg);
            } else {
                outB[(size_t)row * N + col] = f2bf(v);
            }
        }
    }
}

// ---------------------------------------------------------------------------
// Flash attention: one block per (b, h, 64 q-rows). 4 waves, each owns 16 q-rows.
// qkv layout (internal bf16): [token][1536], q|k|v at h*64, 512+h*64, 1024+h*64.
__global__ __launch_bounds__(256) void flash_kernel(const ushort* __restrict__ qkv,
        ushort* __restrict__ o) {
    __shared__ __align__(16) ushort Vt[64][72];      // [d][key]
    __shared__ __align__(16) ushort Pt[4][16][72];   // per-wave P, [q][key]
    int tid = threadIdx.x;
    int wave = tid >> 6, lane = tid & 63;
    int l16 = lane & 15, quad = lane >> 4;
    int bidx = blockIdx.x;
    int qt = bidx & 31;
    int h = (bidx >> 5) & 7;
    int b = bidx >> 8;
    int q0 = qt * 64;
    const size_t base = (size_t)b * 2048 * 1536;

    short8 aq[2];
    {
        int qrow = q0 + wave * 16 + l16;
        const ushort* qp = qkv + base + (size_t)qrow * 1536 + h * 64;
        aq[0] = *(const short8*)(qp + quad * 8);
        aq[1] = *(const short8*)(qp + 32 + quad * 8);
    }
    f32x4 accO[4] = {};
    float mrow[4] = {-INFINITY, -INFINITY, -INFINITY, -INFINITY};
    float lrow[4] = {0.f, 0.f, 0.f, 0.f};
    int vkey = tid & 63, vdb = (tid >> 6) * 16;

    for (int kb = 0; kb < 2048; kb += 64) {
        __syncthreads();   // previous iteration's Vt readers done
        {   // stage V transposed: Vt[d][key]
            const ushort* vp = qkv + base + (size_t)(kb + vkey) * 1536 + 1024 + h * 64 + vdb;
            short8 v0 = *(const short8*)vp;
            short8 v1 = *(const short8*)(vp + 8);
            #pragma unroll
            for (int i = 0; i < 8; i++) Vt[vdb + i][vkey] = (ushort)v0[i];
            #pragma unroll
            for (int i = 0; i < 8; i++) Vt[vdb + 8 + i][vkey] = (ushort)v1[i];
        }
        // S = Q K^T : B-frag straight from global (contiguous d-runs of K rows)
        f32x4 sacc[4] = {};
        #pragma unroll
        for (int c = 0; c < 2; c++) {
            #pragma unroll
            for (int s = 0; s < 4; s++) {
                const ushort* kp = qkv + base + (size_t)(kb + s * 16 + l16) * 1536
                                   + 512 + h * 64 + c * 32 + quad * 8;
                short8 kf = *(const short8*)kp;
                sacc[s] = __builtin_amdgcn_mfma_f32_16x16x32_bf16(aq[c], kf, sacc[s], 0, 0, 0);
            }
        }
        // online softmax per q-row (rows quad*4+r, cols s*16+l16)
        float p[4][4];
        #pragma unroll
        for (int r = 0; r < 4; r++) {
            float tm = fmaxf(fmaxf(sacc[0][r], sacc[1][r]), fmaxf(sacc[2][r], sacc[3][r]));
            #pragma unroll
            for (int off = 1; off < 16; off <<= 1)
                tm = fmaxf(tm, __shfl_xor(tm, off, 16));
            float mn = fmaxf(mrow[r], tm * 0.125f);
            float al = __expf(mrow[r] - mn);
            float rsum = 0.f;
            #pragma unroll
            for (int s = 0; s < 4; s++) {
                float pv = __expf(sacc[s][r] * 0.125f - mn);
                p[s][r] = pv;
                rsum += pv;
            }
            #pragma unroll
            for (int off = 1; off < 16; off <<= 1)
                rsum += __shfl_xor(rsum, off, 16);
            lrow[r] = lrow[r] * al + rsum;
            mrow[r] = mn;
            #pragma unroll
            for (int s = 0; s < 4; s++) accO[s][r] *= al;
        }
        __syncthreads();   // Vt staged & visible
        // P (C-layout) -> LDS -> A-layout, then O += P @ V
        #pragma unroll
        for (int s = 0; s < 4; s++)
            #pragma unroll
            for (int r = 0; r < 4; r++)
                Pt[wave][quad * 4 + r][s * 16 + l16] = f2bf(p[s][r]);
        #pragma unroll
        for (int ks = 0; ks < 2; ks++) {
            short8 ap = *(short8*)&Pt[wave][l16][ks * 32 + quad * 8];
            #pragma unroll
            for (int s = 0; s < 4; s++) {
                short8 vf = *(short8*)&Vt[s * 16 + l16][ks * 32 + quad * 8];
                accO[s] = __builtin_amdgcn_mfma_f32_16x16x32_bf16(ap, vf, accO[s], 0, 0, 0);
            }
        }
    }
    #pragma unroll
    for (int s = 0; s < 4; s++) {
        #pragma unroll
        for (int r = 0; r < 4; r++) {
            int qrow = q0 + wave * 16 + quad * 4 + r;
            float ov = accO[s][r] / lrow[r];
            o[((size_t)(b * 2048 + qrow)) * 512 + h * 64 + s * 16 + l16] = f2bf(ov);
        }
    }
}

// ---------------------------------------------------------------------------
// Output transpose: x3[token][c] f32 -> out[b,t,c,l] f32, LDS tiled 32x32
__global__ __launch_bounds__(256) void tout_kernel(const float* __restrict__ x3,
        float* __restrict__ out) {
    __shared__ float tile[32][33];
    int bt = blockIdx.z;            // 0..15  (b*8+t)
    int l0 = blockIdx.y * 32;       // 0..255
    int c0 = blockIdx.x * 32;       // 0..511
    int tx = threadIdx.x, ty = threadIdx.y;   // 32 x 8
    #pragma unroll
    for (int i = 0; i < 4; i++) {
        int l = ty + i * 8;
        tile[l][tx] = x3[((size_t)bt * 256 + l0 + l) * 512 + c0 + tx];
    }
    __syncthreads();
    #pragma unroll
    for (int i = 0; i < 4; i++) {
        int cc = ty + i * 8;
        out[((size_t)bt * 512 + c0 + cc) * 256 + l0 + tx] = tile[tx][cc];
    }
}

// ---------------------------------------------------------------------------
extern "C" void kernel_launch(void* const* d_in, const int* in_sizes, int n_in,
                              void* d_out, int out_size, void* d_ws, size_t ws_size,
                              hipStream_t stream) {
    const float* in_feat = (const float*)d_in[0];
    const float* qkv_w  = (const float*)d_in[1];
    const float* qkv_b  = (const float*)d_in[2];
    const float* proj_w = (const float*)d_in[3];
    const float* proj_b = (const float*)d_in[4];
    const float* ln1_g  = (const float*)d_in[5];
    const float* ln1_b  = (const float*)d_in[6];
    const float* w1     = (const float*)d_in[7];
    const float* b1     = (const float*)d_in[8];
    const float* w2     = (const float*)d_in[9];
    const float* b2     = (const float*)d_in[10];
    const float* ln2_g  = (const float*)d_in[11];
    const float* ln2_b  = (const float*)d_in[12];

    char* ws = (char*)d_ws;
    float*  x    = (float*) (ws);              // 8 MB residual 1 (reused for final x3)
    float*  x2   = (float*) (ws + 8388608);    // 8 MB residual 2
    ushort* xln  = (ushort*)(ws + 16777216);   // 4 MB LN1 out (bf16)
    ushort* h2   = (ushort*)(ws + 20971520);   // 4 MB LN2 out (bf16)
    ushort* ao   = (ushort*)(ws + 25165824);   // 4 MB attention out (bf16)
    ushort* qkv  = (ushort*)(ws + 29360128);   // 12 MB qkv (bf16)
    ushort* gbuf = (ushort*)(ws + 41943040);   // 16 MB MLP hidden (bf16)

    // 1) transpose + LN1
    prep_kernel<<<4096, 512, 0, stream>>>(in_feat, ln1_g, ln1_b, x, xln);
    // 2) QKV: [4096,512] @ [512,1536] + b -> bf16
    gemm_kernel<EPI_BF16><<<dim3(24, 64), 256, 0, stream>>>(
        xln, qkv_w, qkv_b, nullptr, nullptr, qkv, 4096, 1536, 512);
    // 3) attention
    flash_kernel<<<512, 256, 0, stream>>>(qkv, ao);
    // 4) proj + residual -> f32 x2
    gemm_kernel<EPI_F32RES><<<dim3(8, 64), 256, 0, stream>>>(
        ao, proj_w, proj_b, x, x2, nullptr, 4096, 512, 512);
    // 5) LN2
    ln2_kernel<<<4096, 512, 0, stream>>>(x2, ln2_g, ln2_b, h2);
    // 6) MLP up + GELU -> bf16
    gemm_kernel<EPI_GELU><<<dim3(32, 64), 256, 0, stream>>>(
        h2, w1, b1, nullptr, nullptr, gbuf, 4096, 2048, 512);
    // 7) MLP down + residual -> f32 (into x buffer)
    gemm_kernel<EPI_F32RES><<<dim3(8, 64), 256, 0, stream>>>(
        gbuf, w2, b2, x2, x, nullptr, 4096, 512, 2048);
    // 8) output transpose -> f32 out
    tout_kernel<<<dim3(16, 8, 16), dim3(32, 8), 0, stream>>>(x, (float*)d_out);
}